// Round 9
// baseline (325.233 us; speedup 1.0000x reference)
//
#include <hip/hip_runtime.h>
#include <math.h>

#define CH 64   // channels (C_IN == C_OUT == 64)

typedef __attribute__((ext_vector_type(8))) short bf16x8;
typedef __attribute__((ext_vector_type(4))) float f32x4;

static __device__ __forceinline__ float bf2f(ushort u) {
    union { unsigned int i; float f; } v; v.i = ((unsigned int)u) << 16; return v.f;
}
static __device__ __forceinline__ ushort f2bf(float f) {
    union { float f; unsigned int i; } v; v.f = f;
    unsigned int lsb = (v.i >> 16) & 1;
    v.i += 0x7fffu + lsb;               // round-to-nearest-even
    return (ushort)(v.i >> 16);
}
static __device__ __forceinline__ unsigned int pack2(float a, float b) {
    return (unsigned int)f2bf(a) | ((unsigned int)f2bf(b) << 16);
}
static __device__ __forceinline__ float lo16(unsigned int u) { return bf2f((ushort)(u & 0xffffu)); }
static __device__ __forceinline__ float hi16(unsigned int u) { return bf2f((ushort)(u >> 16)); }

// ---- fp8 e4m3fn helpers (RNE encode, flush-subnormal decode-to-zero) ----
static __device__ __forceinline__ unsigned int f2fp8(float f) {
    unsigned int b = __float_as_uint(f);
    unsigned int s = (b >> 24) & 0x80u;
    unsigned int a = b & 0x7FFFFFFFu;
    a = a > 0x43E00000u ? 0x43E00000u : a;            // clamp |x| <= 448
    unsigned int r = a + 0x7FFFFu + ((a >> 20) & 1u); // RNE at bit 20
    if (r < (121u << 23)) return s;                    // underflow -> +/-0
    unsigned int e = (r >> 23) - 120u;                 // 1..15
    unsigned int m = (r >> 20) & 7u;
    return s | (e << 3) | m;
}
static __device__ __forceinline__ float fp82f(unsigned int u) {
    unsigned int f = ((u & 0x80u) << 24) | (((u & 0x7Fu) << 20) + 0x3C000000u);
    return (u & 0x78u) ? __uint_as_float(f) : 0.f;
}

// ---------------- fused init: degree+hist+rank | bf16+fp8 cast | weight pack ----------------

__global__ __launch_bounds__(256) void k_init(
    const int* __restrict__ src, const int* __restrict__ dst,
    const float* __restrict__ w,
    float* __restrict__ deg, int* __restrict__ cnt, int* __restrict__ erank, int E,
    const float4* __restrict__ X, const float4* __restrict__ H,
    ushort* __restrict__ XHb, unsigned char* __restrict__ XH8, int total4,
    const float* __restrict__ Wxz, const float* __restrict__ Whz,
    const float* __restrict__ Wxr, const float* __restrict__ Whr,
    const float* __restrict__ Wxh, const float* __restrict__ Whh,
    ushort* __restrict__ Bp, int bE, int bC)
{
    int b = blockIdx.x;
    int tid = threadIdx.x;
    if (b < bE) {
        int i = b * 256 + tid;
        if (i < E) {
            atomicAdd(&deg[src[i]], w[i]);
            erank[i] = atomicAdd(&cnt[dst[i]], 1);
        }
    } else if (b < bE + bC) {
        // cast X,H -> bf16 interleaved [X(64)|H(64)] + fp8 mirror
        int i = (b - bE) * 256 + tid;
        if (i < total4) {
            float4 x = X[i], h = H[i];
            int node = i >> 4, c4 = i & 15;
            ushort4 xb, hb;
            xb.x = f2bf(x.x); xb.y = f2bf(x.y); xb.z = f2bf(x.z); xb.w = f2bf(x.w);
            hb.x = f2bf(h.x); hb.y = f2bf(h.y); hb.z = f2bf(h.z); hb.w = f2bf(h.w);
            *(ushort4*)(XHb + (size_t)node * 128 + c4 * 4)      = xb;
            *(ushort4*)(XHb + (size_t)node * 128 + 64 + c4 * 4) = hb;
            unsigned int x8 = f2fp8(x.x) | (f2fp8(x.y) << 8) | (f2fp8(x.z) << 16) | (f2fp8(x.w) << 24);
            unsigned int h8 = f2fp8(h.x) | (f2fp8(h.y) << 8) | (f2fp8(h.z) << 16) | (f2fp8(h.w) << 24);
            *(unsigned int*)(XH8 + (size_t)node * 128 + c4 * 4)      = x8;
            *(unsigned int*)(XH8 + (size_t)node * 128 + 64 + c4 * 4) = h8;
        }
    } else {
        // pack weights: Bp[mtg][ct][lane][e]; mtg: z=0..11, r=12..23, h(x)=24..29, hh=30..35
        int mtg = b - bE - bC;
        int ct = tid >> 6;
        int lane = tid & 63;
        const float* W; int m, kt;
        if (mtg < 12)      { int l = mtg;      m = l >> 1; kt = l & 1; W = (m < 3) ? Wxz + m * 4096 : Whz + (m - 3) * 4096; }
        else if (mtg < 24) { int l = mtg - 12; m = l >> 1; kt = l & 1; W = (m < 3) ? Wxr + m * 4096 : Whr + (m - 3) * 4096; }
        else if (mtg < 30) { int l = mtg - 24; m = l >> 1; kt = l & 1; W = Wxh + m * 4096; }
        else               { int l = mtg - 30; m = l >> 1; kt = l & 1; W = Whh + m * 4096; }
        int cout = ct * 16 + (lane & 15);
        ushort* dstp = Bp + ((((mtg * 4) + ct) * 64 + lane) << 3);
        #pragma unroll
        for (int e = 0; e < 8; ++e) {
            int cin = kt * 32 + ((lane >> 4) << 3) + e;
            dstp[e] = f2bf(W[cin * 64 + cout]);
        }
    }
}

// ---------------- 3-phase multi-block scan ----------------

__global__ __launch_bounds__(256) void k_scanA(const int* __restrict__ cnt,
                                               int* __restrict__ rowptr,
                                               int* __restrict__ bsum, int N) {
    __shared__ int ts[256];
    int tid = threadIdx.x;
    int base = blockIdx.x * 2048 + tid * 8;
    int v[8]; int s = 0;
    #pragma unroll
    for (int k = 0; k < 8; ++k) { int i = base + k; v[k] = (i < N) ? cnt[i] : 0; s += v[k]; }
    ts[tid] = s;
    __syncthreads();
    for (int off = 1; off < 256; off <<= 1) {
        int t = (tid >= off) ? ts[tid - off] : 0;
        __syncthreads();
        ts[tid] += t;
        __syncthreads();
    }
    int run = ts[tid] - s;
    #pragma unroll
    for (int k = 0; k < 8; ++k) { int i = base + k; if (i < N) rowptr[i] = run; run += v[k]; }
    if (tid == 255) bsum[blockIdx.x] = ts[255];
}

__global__ void k_scanB(int* __restrict__ bsum, int B) {
    int lane = threadIdx.x;
    int v = (lane < B) ? bsum[lane] : 0;
    int incl = v;
    #pragma unroll
    for (int off = 1; off < 64; off <<= 1) {
        int t = __shfl_up(incl, off, 64);
        if (lane >= off) incl += t;
    }
    if (lane < B) bsum[lane] = incl - v;
    if (lane == B - 1) bsum[B] = incl;
}

__global__ __launch_bounds__(256) void k_scanC(int* __restrict__ rowptr,
                                               const int* __restrict__ bsum,
                                               float* __restrict__ deg, int N, int B) {
    int base = blockIdx.x * 2048 + threadIdx.x * 8;
    int add = bsum[blockIdx.x];
    #pragma unroll
    for (int k = 0; k < 8; ++k) {
        int i = base + k;
        if (i < N) {
            rowptr[i] += add;
            float d = deg[i];
            deg[i] = (d > 0.f) ? rsqrtf(fmaxf(d, 1e-12f)) : 0.f;
        }
    }
    if (blockIdx.x == 0 && threadIdx.x == 0) rowptr[N] = bsum[B];
}

// ---------------- atomic-free scatter: pos = rowptr[dst] + rank ----------------

__global__ __launch_bounds__(256) void k_scatter(const int* __restrict__ src,
                                                 const int* __restrict__ dst,
                                                 const float* __restrict__ w,
                                                 const float* __restrict__ dis,
                                                 const int* __restrict__ rowptr,
                                                 const int* __restrict__ erank,
                                                 int2* __restrict__ emeta, int E) {
    int e = blockIdx.x * 256 + threadIdx.x;
    if (e < E) {
        int d = dst[e], s = src[e];
        int pos = rowptr[d] + erank[e];
        float lw = -dis[s] * w[e] * dis[d];
        emeta[pos] = make_int2(s, __float_as_int(lw));
    }
}

// ---------------- CSR propagation, dual (fp8 gather, 128B/edge) ----------------
// one wave per node; lane = ushort = 2 fp8 channels; unroll 4

#define DSTEP(mm) { \
    unsigned int p = t8[(size_t)(mm).x * 64 + lane]; \
    float l = __int_as_float((mm).y); \
    ax = fmaf(l, fp82f(p & 0xFFu), ax); ay = fmaf(l, fp82f(p >> 8), ay); }

__global__ __launch_bounds__(256) void k_prop_dual(const int* __restrict__ rowptr,
                                                   const int2* __restrict__ emeta,
                                                   const ushort* __restrict__ t8,
                                                   unsigned int* __restrict__ o,
                                                   ushort* __restrict__ o8, int N) {
    int wid = (blockIdx.x * 256 + threadIdx.x) >> 6;
    int lane = threadIdx.x & 63;
    if (wid >= N) return;
    int beg = rowptr[wid], end = rowptr[wid + 1];
    float ax = 0.f, ay = 0.f;
    int j = beg;
    for (; j + 3 < end; j += 4) {
        int2 m0 = emeta[j], m1 = emeta[j + 1], m2 = emeta[j + 2], m3 = emeta[j + 3];
        DSTEP(m0) DSTEP(m1) DSTEP(m2) DSTEP(m3)
    }
    for (; j < end; ++j) { int2 m = emeta[j]; DSTEP(m) }
    size_t oi = (size_t)wid * 64 + lane;
    o[oi] = pack2(ax, ay);
    o8[oi] = (ushort)(f2fp8(ax) | (f2fp8(ay) << 8));
}

__global__ __launch_bounds__(256) void k_prop_dual2(const int* __restrict__ rowptr,
                                                    const int2* __restrict__ emeta,
                                                    const ushort* __restrict__ t8,
                                                    const unsigned int* __restrict__ t0,
                                                    unsigned int* __restrict__ o, int N) {
    int wid = (blockIdx.x * 256 + threadIdx.x) >> 6;
    int lane = threadIdx.x & 63;
    if (wid >= N) return;
    int beg = rowptr[wid], end = rowptr[wid + 1];
    float ax = 0.f, ay = 0.f;
    int j = beg;
    for (; j + 3 < end; j += 4) {
        int2 m0 = emeta[j], m1 = emeta[j + 1], m2 = emeta[j + 2], m3 = emeta[j + 3];
        DSTEP(m0) DSTEP(m1) DSTEP(m2) DSTEP(m3)
    }
    for (; j < end; ++j) { int2 m = emeta[j]; DSTEP(m) }
    size_t oi = (size_t)wid * 64 + lane;
    unsigned int z = t0[oi];
    o[oi] = pack2(2.f * ax - lo16(z), 2.f * ay - hi16(z));
}

// ---------------- CSR propagation, single feature (H*R): 2 nodes/wave, fp8 gather ----------------
// 32-lane subgroup per node; lane = ushort = 2 fp8 channels (64B/edge); unroll 4

#define HSTEP(mm) { \
    unsigned int p = t8[(size_t)(mm).x * 32 + sl]; \
    float l = __int_as_float((mm).y); \
    ax = fmaf(l, fp82f(p & 0xFFu), ax); ay = fmaf(l, fp82f(p >> 8), ay); }

__global__ __launch_bounds__(256) void k_prop1(const int* __restrict__ rowptr,
                                               const int2* __restrict__ emeta,
                                               const ushort* __restrict__ t8,
                                               unsigned int* __restrict__ out,
                                               ushort* __restrict__ out8, int N) {
    int wv = (blockIdx.x * 256 + threadIdx.x) >> 6;
    int lane = threadIdx.x & 63;
    int node = wv * 2 + (lane >> 5);
    int sl = lane & 31;
    if (node >= N) return;
    int beg = rowptr[node], end = rowptr[node + 1];
    float ax = 0.f, ay = 0.f;
    int j = beg;
    for (; j + 3 < end; j += 4) {
        int2 m0 = emeta[j], m1 = emeta[j + 1], m2 = emeta[j + 2], m3 = emeta[j + 3];
        HSTEP(m0) HSTEP(m1) HSTEP(m2) HSTEP(m3)
    }
    for (; j < end; ++j) { int2 m = emeta[j]; HSTEP(m) }
    size_t oi = (size_t)node * 32 + sl;
    out[oi] = pack2(ax, ay);
    out8[oi] = (ushort)(f2fp8(ax) | (f2fp8(ay) << 8));
}

__global__ __launch_bounds__(256) void k_prop2(const int* __restrict__ rowptr,
                                               const int2* __restrict__ emeta,
                                               const ushort* __restrict__ t8,
                                               const unsigned int* __restrict__ t0,
                                               unsigned int* __restrict__ out, int N) {
    int wv = (blockIdx.x * 256 + threadIdx.x) >> 6;
    int lane = threadIdx.x & 63;
    int node = wv * 2 + (lane >> 5);
    int sl = lane & 31;
    if (node >= N) return;
    int beg = rowptr[node], end = rowptr[node + 1];
    float ax = 0.f, ay = 0.f;
    int j = beg;
    for (; j + 3 < end; j += 4) {
        int2 m0 = emeta[j], m1 = emeta[j + 1], m2 = emeta[j + 2], m3 = emeta[j + 3];
        HSTEP(m0) HSTEP(m1) HSTEP(m2) HSTEP(m3)
    }
    for (; j < end; ++j) { int2 m = emeta[j]; HSTEP(m) }
    size_t oi = (size_t)node * 32 + sl;
    unsigned int z = t0[oi];
    out[oi] = pack2(2.f * ax - lo16(z), 2.f * ay - hi16(z));
}

// ---------------- MFMA GEMM helpers ----------------
// wave computes 32 rows x 64 cols; k-slot: k = kt*32 + (lane>>4)*8 + e

static __device__ __forceinline__ bf16x8 ldA(const ushort* __restrict__ t, int stride,
                                             int row0, int lane, int kt, int N) {
    int row = row0 + (lane & 15);
    bf16x8 v = {};
    if (row < N) v = *(const bf16x8*)(t + (size_t)row * stride + kt * 32 + ((lane >> 4) << 3));
    return v;
}
static __device__ __forceinline__ bf16x8 ldB(const ushort* __restrict__ bp,
                                             int mt, int ct, int lane) {
    return *(const bf16x8*)(bp + ((((mt * 4) + ct) * 64 + lane) << 3));
}

#define MFMA(a, b, c) __builtin_amdgcn_mfma_f32_16x16x32_bf16(a, b, c, 0, 0, 0)

// ---------------- Pass A: Z(bf16), HR(bf16+fp8), preH(bf16) ----------------

__global__ __launch_bounds__(256) void k_gA(
    const ushort* __restrict__ XHb, const ushort* __restrict__ T1xh, const ushort* __restrict__ T2xh,
    const ushort* __restrict__ Bp,
    const float* __restrict__ bxz, const float* __restrict__ bhz,
    const float* __restrict__ bxr, const float* __restrict__ bhr,
    const float* __restrict__ bxh,
    ushort* __restrict__ Zb, ushort* __restrict__ HRb, unsigned char* __restrict__ HR8,
    ushort* __restrict__ preHb, int N)
{
    int wid = blockIdx.x * 4 + (threadIdx.x >> 6);
    int lane = threadIdx.x & 63;
    int row0 = wid * 32;
    if (row0 >= N) return;

    f32x4 accZ[2][4], accR[2][4], accH[2][4];
    #pragma unroll
    for (int ct = 0; ct < 4; ++ct) {
        int col = ct * 16 + (lane & 15);
        float bz = bxz[col] + bhz[col];
        float br = bxr[col] + bhr[col];
        float bh = bxh[col];
        #pragma unroll
        for (int rt = 0; rt < 2; ++rt) {
            accZ[rt][ct] = (f32x4){bz, bz, bz, bz};
            accR[rt][ct] = (f32x4){br, br, br, br};
            accH[rt][ct] = (f32x4){bh, bh, bh, bh};
        }
    }

    const ushort* ins[6] = { XHb, T1xh, T2xh, XHb + 64, T1xh + 64, T2xh + 64 };

    #pragma unroll
    for (int m = 0; m < 6; ++m) {
        #pragma unroll
        for (int kt = 0; kt < 2; ++kt) {
            bf16x8 a0 = ldA(ins[m], 128, row0,      lane, kt, N);
            bf16x8 a1 = ldA(ins[m], 128, row0 + 16, lane, kt, N);
            int mt = m * 2 + kt;
            #pragma unroll
            for (int ct = 0; ct < 4; ++ct) {
                bf16x8 bz8 = ldB(Bp, mt, ct, lane);
                accZ[0][ct] = MFMA(a0, bz8, accZ[0][ct]);
                accZ[1][ct] = MFMA(a1, bz8, accZ[1][ct]);
                bf16x8 br8 = ldB(Bp, 12 + mt, ct, lane);
                accR[0][ct] = MFMA(a0, br8, accR[0][ct]);
                accR[1][ct] = MFMA(a1, br8, accR[1][ct]);
                if (m < 3) {
                    bf16x8 bh8 = ldB(Bp, 24 + mt, ct, lane);
                    accH[0][ct] = MFMA(a0, bh8, accH[0][ct]);
                    accH[1][ct] = MFMA(a1, bh8, accH[1][ct]);
                }
            }
        }
    }

    #pragma unroll
    for (int rt = 0; rt < 2; ++rt) {
        #pragma unroll
        for (int ct = 0; ct < 4; ++ct) {
            int col = ct * 16 + (lane & 15);
            #pragma unroll
            for (int r = 0; r < 4; ++r) {
                int row = row0 + rt * 16 + ((lane >> 4) << 2) + r;
                if (row < N) {
                    int o = row * CH + col;
                    float z = 1.f / (1.f + expf(-accZ[rt][ct][r]));
                    float rr = 1.f / (1.f + expf(-accR[rt][ct][r]));
                    float h = bf2f(XHb[(size_t)row * 128 + 64 + col]);   // H in bf16
                    float hr = h * rr;
                    Zb[o] = f2bf(z);
                    HRb[o] = f2bf(hr);
                    HR8[o] = (unsigned char)f2fp8(hr);
                    preHb[o] = f2bf(accH[rt][ct][r]);
                }
            }
        }
    }
}

// ---------------- Pass B: H_new = Z*H + (1-Z)*tanh(preH + hh-conv) ----------------

__global__ __launch_bounds__(256) void k_gB(
    const ushort* __restrict__ HRb, const ushort* __restrict__ T1, const ushort* __restrict__ T2,
    const ushort* __restrict__ Bp, const float* __restrict__ bhh,
    const ushort* __restrict__ Zb, const float* __restrict__ H,
    const ushort* __restrict__ preHb, float* __restrict__ out, int N)
{
    int wid = blockIdx.x * 4 + (threadIdx.x >> 6);
    int lane = threadIdx.x & 63;
    int row0 = wid * 32;
    if (row0 >= N) return;

    f32x4 acc[2][4];
    #pragma unroll
    for (int ct = 0; ct < 4; ++ct) {
        int col = ct * 16 + (lane & 15);
        float bh = bhh[col];
        #pragma unroll
        for (int rt = 0; rt < 2; ++rt) acc[rt][ct] = (f32x4){bh, bh, bh, bh};
    }

    const ushort* ins[3] = { HRb, T1, T2 };

    #pragma unroll
    for (int m = 0; m < 3; ++m) {
        #pragma unroll
        for (int kt = 0; kt < 2; ++kt) {
            bf16x8 a0 = ldA(ins[m], 64, row0,      lane, kt, N);
            bf16x8 a1 = ldA(ins[m], 64, row0 + 16, lane, kt, N);
            int mt = 30 + m * 2 + kt;
            #pragma unroll
            for (int ct = 0; ct < 4; ++ct) {
                bf16x8 b8 = ldB(Bp, mt, ct, lane);
                acc[0][ct] = MFMA(a0, b8, acc[0][ct]);
                acc[1][ct] = MFMA(a1, b8, acc[1][ct]);
            }
        }
    }

    #pragma unroll
    for (int rt = 0; rt < 2; ++rt) {
        #pragma unroll
        for (int ct = 0; ct < 4; ++ct) {
            int col = ct * 16 + (lane & 15);
            #pragma unroll
            for (int r = 0; r < 4; ++r) {
                int row = row0 + rt * 16 + ((lane >> 4) << 2) + r;
                if (row < N) {
                    int o = row * CH + col;
                    float pre = acc[rt][ct][r] + bf2f(preHb[o]);
                    float z = bf2f(Zb[o]);
                    float h = H[o];
                    out[o] = z * h + (1.f - z) * tanhf(pre);
                }
            }
        }
    }
}

// ---------------- launch ----------------

extern "C" void kernel_launch(void* const* d_in, const int* in_sizes, int n_in,
                              void* d_out, int out_size, void* d_ws, size_t ws_size,
                              hipStream_t stream) {
    const float* X   = (const float*)d_in[0];
    const int*   ei  = (const int*)d_in[1];
    const float* ew  = (const float*)d_in[2];
    const float* H   = (const float*)d_in[3];
    const float* Wxz = (const float*)d_in[4];
    const float* bxz = (const float*)d_in[5];
    const float* Whz = (const float*)d_in[6];
    const float* bhz = (const float*)d_in[7];
    const float* Wxr = (const float*)d_in[8];
    const float* bxr = (const float*)d_in[9];
    const float* Whr = (const float*)d_in[10];
    const float* bhr = (const float*)d_in[11];
    const float* Wxh = (const float*)d_in[12];
    const float* bxh = (const float*)d_in[13];
    const float* Whh = (const float*)d_in[14];
    const float* bhh = (const float*)d_in[15];

    const int N = in_sizes[0] / CH;
    const int E = in_sizes[2];
    const long long NC = (long long)N * CH;

    const int* srcI = ei;
    const int* dstI = ei + E;

    // ---- workspace layout ----
    char* p = (char*)d_ws;
    auto alloc = [&](size_t bytes) { char* r = p; p += (bytes + 255) & ~(size_t)255; return r; };
    int*    rowptr = (int*)alloc((size_t)(N + 1) * 4);
    int2*   emeta  = (int2*)alloc((size_t)E * 8);
    int*    erank  = (int*)alloc((size_t)E * 4);
    float*  deg    = (float*)alloc((size_t)N * 8);      // deg (N) + cnt (N), contiguous
    int*    cnt    = (int*)(deg + N);
    int*    bsum   = (int*)alloc(256 * 4);
    ushort* Bp     = (ushort*)alloc((size_t)36 * 4 * 64 * 8 * 2);
    ushort* XHb    = (ushort*)alloc((size_t)NC * 2 * 2);   // bf16 interleaved X|H [N][128]
    ushort* T1xh   = (ushort*)alloc((size_t)NC * 2 * 2);   // bf16 [N][128]
    ushort* T2xh   = (ushort*)alloc((size_t)NC * 2 * 2);   // bf16 [N][128]
    unsigned char* XH8 = (unsigned char*)alloc((size_t)NC * 2);  // fp8 [N][128]
    unsigned char* T18 = (unsigned char*)alloc((size_t)NC * 2);  // fp8 [N][128]
    ushort* HRb    = (ushort*)alloc((size_t)NC * 2);       // bf16 [N][64]
    ushort* Zb     = (ushort*)alloc((size_t)NC * 2);
    ushort* preHb  = (ushort*)alloc((size_t)NC * 2);
    // aliases into buffers dead after gA / dual2:
    ushort* T1r  = T1xh;                 // bf16 [N][64] (fits in 12.8MB buffer)
    ushort* T2r  = T2xh;                 // bf16 [N][64]
    unsigned char* HR8  = XH8;           // fp8 [N][64]  (XH8 dead after dual1)
    unsigned char* T1r8 = T18;           // fp8 [N][64]  (T18 dead after dual2)

    const int total4 = (int)(NC / 4);
    const int bE = (E + 255) / 256;
    const int bC = (total4 + 255) / 256;
    const int B  = (N + 2047) / 2048;                    // scan blocks (<=64)
    const int bW = (int)((N * 64 + 255) / 256);          // one wave per node
    const int bW2 = (int)((((N + 1) / 2) * 64 + 255) / 256); // 2 nodes per wave
    const int nW = (N + 31) / 32;
    const int bG = (nW + 3) / 4;

    // fused init: degree+hist+rank | cast | pack
    hipMemsetAsync(deg, 0, (size_t)N * 8, stream);
    k_init<<<bE + bC + 36, 256, 0, stream>>>(srcI, dstI, ew, deg, cnt, erank, E,
                                             (const float4*)X, (const float4*)H, XHb, XH8, total4,
                                             Wxz, Whz, Wxr, Whr, Wxh, Whh, Bp, bE, bC);

    // multi-block scan (+ fused rsqrt)
    k_scanA<<<B, 256, 0, stream>>>(cnt, rowptr, bsum, N);
    k_scanB<<<1, 64, 0, stream>>>(bsum, B);
    k_scanC<<<B, 256, 0, stream>>>(rowptr, bsum, deg, N, B);

    // atomic-free CSR scatter
    k_scatter<<<bE, 256, 0, stream>>>(srcI, dstI, ew, deg, rowptr, erank, emeta, E);

    // Chebyshev bases for X and H (fp8 gathers)
    k_prop_dual <<<bW, 256, 0, stream>>>(rowptr, emeta, (const ushort*)XH8,
                                         (unsigned int*)T1xh, (ushort*)T18, N);
    k_prop_dual2<<<bW, 256, 0, stream>>>(rowptr, emeta, (const ushort*)T18,
                                         (const unsigned int*)XHb, (unsigned int*)T2xh, N);

    // Pass A: Z, H*R (bf16+fp8), preH
    k_gA<<<bG, 256, 0, stream>>>(XHb, T1xh, T2xh, Bp,
                                 bxz, bhz, bxr, bhr, bxh,
                                 Zb, HRb, HR8, preHb, N);

    // Chebyshev bases for H*R (fp8 gathers; outputs alias dead buffers)
    k_prop1<<<bW2, 256, 0, stream>>>(rowptr, emeta, (const ushort*)HR8,
                                     (unsigned int*)T1r, (ushort*)T1r8, N);
    k_prop2<<<bW2, 256, 0, stream>>>(rowptr, emeta, (const ushort*)T1r8,
                                     (const unsigned int*)HRb, (unsigned int*)T2r, N);

    // Pass B: H_new
    k_gB<<<bG, 256, 0, stream>>>(HRb, T1r, T2r, Bp, bhh, Zb, H, preHb, (float*)d_out, N);
}

// Round 10
// 288.259 us; speedup vs baseline: 1.1283x; 1.1283x over previous
//
#include <hip/hip_runtime.h>
#include <math.h>

#define CH 64   // channels (C_IN == C_OUT == 64)

typedef __attribute__((ext_vector_type(8))) short bf16x8;
typedef __attribute__((ext_vector_type(4))) float f32x4;

static __device__ __forceinline__ float bf2f(ushort u) {
    union { unsigned int i; float f; } v; v.i = ((unsigned int)u) << 16; return v.f;
}
static __device__ __forceinline__ ushort f2bf(float f) {
    union { float f; unsigned int i; } v; v.f = f;
    unsigned int lsb = (v.i >> 16) & 1;
    v.i += 0x7fffu + lsb;               // round-to-nearest-even
    return (ushort)(v.i >> 16);
}
static __device__ __forceinline__ unsigned int pack2(float a, float b) {
    return (unsigned int)f2bf(a) | ((unsigned int)f2bf(b) << 16);
}
static __device__ __forceinline__ float lo16(unsigned int u) { return bf2f((ushort)(u & 0xffffu)); }
static __device__ __forceinline__ float hi16(unsigned int u) { return bf2f((ushort)(u >> 16)); }

// ---------------- fused init: degree+hist+rank | bf16 cast | weight pack ----------------

__global__ __launch_bounds__(256) void k_init(
    const int* __restrict__ src, const int* __restrict__ dst,
    const float* __restrict__ w,
    float* __restrict__ deg, int* __restrict__ cnt, int* __restrict__ erank, int E,
    const float4* __restrict__ X, const float4* __restrict__ H,
    ushort* __restrict__ XHb, int total4,
    const float* __restrict__ Wxz, const float* __restrict__ Whz,
    const float* __restrict__ Wxr, const float* __restrict__ Whr,
    const float* __restrict__ Wxh, const float* __restrict__ Whh,
    ushort* __restrict__ Bp, int bE, int bC)
{
    int b = blockIdx.x;
    int tid = threadIdx.x;
    if (b < bE) {
        // degree over src, histogram+rank over dst
        int i = b * 256 + tid;
        if (i < E) {
            atomicAdd(&deg[src[i]], w[i]);
            erank[i] = atomicAdd(&cnt[dst[i]], 1);
        }
    } else if (b < bE + bC) {
        // cast X,H -> bf16, interleaved rows [X(64)|H(64)]
        int i = (b - bE) * 256 + tid;
        if (i < total4) {
            float4 x = X[i], h = H[i];
            int node = i >> 4, c4 = i & 15;
            ushort4 xb, hb;
            xb.x = f2bf(x.x); xb.y = f2bf(x.y); xb.z = f2bf(x.z); xb.w = f2bf(x.w);
            hb.x = f2bf(h.x); hb.y = f2bf(h.y); hb.z = f2bf(h.z); hb.w = f2bf(h.w);
            *(ushort4*)(XHb + (size_t)node * 128 + c4 * 4)      = xb;
            *(ushort4*)(XHb + (size_t)node * 128 + 64 + c4 * 4) = hb;
        }
    } else {
        // pack weights: Bp[mtg][ct][lane][e]; mtg: z=0..11, r=12..23, h(x)=24..29, hh=30..35
        // k-slot: k = kt*32 + (lane>>4)*8 + e (consistent A/B convention)
        int mtg = b - bE - bC;
        int ct = tid >> 6;
        int lane = tid & 63;
        const float* W; int m, kt;
        if (mtg < 12)      { int l = mtg;      m = l >> 1; kt = l & 1; W = (m < 3) ? Wxz + m * 4096 : Whz + (m - 3) * 4096; }
        else if (mtg < 24) { int l = mtg - 12; m = l >> 1; kt = l & 1; W = (m < 3) ? Wxr + m * 4096 : Whr + (m - 3) * 4096; }
        else if (mtg < 30) { int l = mtg - 24; m = l >> 1; kt = l & 1; W = Wxh + m * 4096; }
        else               { int l = mtg - 30; m = l >> 1; kt = l & 1; W = Whh + m * 4096; }
        int cout = ct * 16 + (lane & 15);
        ushort* dstp = Bp + ((((mtg * 4) + ct) * 64 + lane) << 3);
        #pragma unroll
        for (int e = 0; e < 8; ++e) {
            int cin = kt * 32 + ((lane >> 4) << 3) + e;
            dstp[e] = f2bf(W[cin * 64 + cout]);
        }
    }
}

// ---------------- 3-phase multi-block scan ----------------

__global__ __launch_bounds__(256) void k_scanA(const int* __restrict__ cnt,
                                               int* __restrict__ rowptr,
                                               int* __restrict__ bsum, int N) {
    __shared__ int ts[256];
    int tid = threadIdx.x;
    int base = blockIdx.x * 2048 + tid * 8;
    int v[8]; int s = 0;
    #pragma unroll
    for (int k = 0; k < 8; ++k) { int i = base + k; v[k] = (i < N) ? cnt[i] : 0; s += v[k]; }
    ts[tid] = s;
    __syncthreads();
    for (int off = 1; off < 256; off <<= 1) {
        int t = (tid >= off) ? ts[tid - off] : 0;
        __syncthreads();
        ts[tid] += t;
        __syncthreads();
    }
    int run = ts[tid] - s;
    #pragma unroll
    for (int k = 0; k < 8; ++k) { int i = base + k; if (i < N) rowptr[i] = run; run += v[k]; }
    if (tid == 255) bsum[blockIdx.x] = ts[255];
}

// wave-parallel scan of block sums (B <= 64)
__global__ void k_scanB(int* __restrict__ bsum, int B) {
    int lane = threadIdx.x;
    int v = (lane < B) ? bsum[lane] : 0;
    int incl = v;
    #pragma unroll
    for (int off = 1; off < 64; off <<= 1) {
        int t = __shfl_up(incl, off, 64);
        if (lane >= off) incl += t;
    }
    if (lane < B) bsum[lane] = incl - v;
    if (lane == B - 1) bsum[B] = incl;
}

__global__ __launch_bounds__(256) void k_scanC(int* __restrict__ rowptr,
                                               const int* __restrict__ bsum,
                                               float* __restrict__ deg, int N, int B) {
    int base = blockIdx.x * 2048 + threadIdx.x * 8;
    int add = bsum[blockIdx.x];
    #pragma unroll
    for (int k = 0; k < 8; ++k) {
        int i = base + k;
        if (i < N) {
            rowptr[i] += add;
            float d = deg[i];
            deg[i] = (d > 0.f) ? rsqrtf(fmaxf(d, 1e-12f)) : 0.f;
        }
    }
    if (blockIdx.x == 0 && threadIdx.x == 0) rowptr[N] = bsum[B];
}

// ---------------- atomic-free scatter: pos = rowptr[dst] + rank ----------------

__global__ __launch_bounds__(256) void k_scatter(const int* __restrict__ src,
                                                 const int* __restrict__ dst,
                                                 const float* __restrict__ w,
                                                 const float* __restrict__ dis,
                                                 const int* __restrict__ rowptr,
                                                 const int* __restrict__ erank,
                                                 int2* __restrict__ emeta, int E) {
    int e = blockIdx.x * 256 + threadIdx.x;
    if (e < E) {
        int d = dst[e], s = src[e];
        int pos = rowptr[d] + erank[e];
        float lw = -dis[s] * w[e] * dis[d];
        emeta[pos] = make_int2(s, __float_as_int(lw));
    }
}

// ---------------- CSR propagation, dual (interleaved X|H rows, 256B/edge) ----------------
// one wave per node; lane = uint = 2 bf16 channels; unroll 4.
// beg/end are wave-uniform (1 wave = 1 node): readfirstlane -> scalar emeta loads.

__global__ __launch_bounds__(256) void k_prop_dual(const int* __restrict__ rowptr,
                                                   const int2* __restrict__ emeta,
                                                   const unsigned int* __restrict__ t,
                                                   unsigned int* __restrict__ o, int N) {
    int wid = (blockIdx.x * 256 + threadIdx.x) >> 6;
    int lane = threadIdx.x & 63;
    if (wid >= N) return;
    int beg = __builtin_amdgcn_readfirstlane(rowptr[wid]);
    int end = __builtin_amdgcn_readfirstlane(rowptr[wid + 1]);
    float ax = 0.f, ay = 0.f;
    int j = beg;
    for (; j + 3 < end; j += 4) {
        int2 m0 = emeta[j], m1 = emeta[j + 1], m2 = emeta[j + 2], m3 = emeta[j + 3];
        unsigned int p0 = t[(size_t)m0.x * 64 + lane];
        unsigned int p1 = t[(size_t)m1.x * 64 + lane];
        unsigned int p2 = t[(size_t)m2.x * 64 + lane];
        unsigned int p3 = t[(size_t)m3.x * 64 + lane];
        float l0 = __int_as_float(m0.y), l1 = __int_as_float(m1.y);
        float l2 = __int_as_float(m2.y), l3 = __int_as_float(m3.y);
        ax = fmaf(l0, lo16(p0), ax); ay = fmaf(l0, hi16(p0), ay);
        ax = fmaf(l1, lo16(p1), ax); ay = fmaf(l1, hi16(p1), ay);
        ax = fmaf(l2, lo16(p2), ax); ay = fmaf(l2, hi16(p2), ay);
        ax = fmaf(l3, lo16(p3), ax); ay = fmaf(l3, hi16(p3), ay);
    }
    for (; j < end; ++j) {
        int2 m = emeta[j];
        unsigned int p = t[(size_t)m.x * 64 + lane];
        float l = __int_as_float(m.y);
        ax = fmaf(l, lo16(p), ax); ay = fmaf(l, hi16(p), ay);
    }
    o[(size_t)wid * 64 + lane] = pack2(ax, ay);
}

__global__ __launch_bounds__(256) void k_prop_dual2(const int* __restrict__ rowptr,
                                                    const int2* __restrict__ emeta,
                                                    const unsigned int* __restrict__ t,
                                                    const unsigned int* __restrict__ t0,
                                                    unsigned int* __restrict__ o, int N) {
    int wid = (blockIdx.x * 256 + threadIdx.x) >> 6;
    int lane = threadIdx.x & 63;
    if (wid >= N) return;
    int beg = __builtin_amdgcn_readfirstlane(rowptr[wid]);
    int end = __builtin_amdgcn_readfirstlane(rowptr[wid + 1]);
    float ax = 0.f, ay = 0.f;
    int j = beg;
    for (; j + 3 < end; j += 4) {
        int2 m0 = emeta[j], m1 = emeta[j + 1], m2 = emeta[j + 2], m3 = emeta[j + 3];
        unsigned int p0 = t[(size_t)m0.x * 64 + lane];
        unsigned int p1 = t[(size_t)m1.x * 64 + lane];
        unsigned int p2 = t[(size_t)m2.x * 64 + lane];
        unsigned int p3 = t[(size_t)m3.x * 64 + lane];
        float l0 = __int_as_float(m0.y), l1 = __int_as_float(m1.y);
        float l2 = __int_as_float(m2.y), l3 = __int_as_float(m3.y);
        ax = fmaf(l0, lo16(p0), ax); ay = fmaf(l0, hi16(p0), ay);
        ax = fmaf(l1, lo16(p1), ax); ay = fmaf(l1, hi16(p1), ay);
        ax = fmaf(l2, lo16(p2), ax); ay = fmaf(l2, hi16(p2), ay);
        ax = fmaf(l3, lo16(p3), ax); ay = fmaf(l3, hi16(p3), ay);
    }
    for (; j < end; ++j) {
        int2 m = emeta[j];
        unsigned int p = t[(size_t)m.x * 64 + lane];
        float l = __int_as_float(m.y);
        ax = fmaf(l, lo16(p), ax); ay = fmaf(l, hi16(p), ay);
    }
    size_t oi = (size_t)wid * 64 + lane;
    unsigned int z = t0[oi];
    o[oi] = pack2(2.f * ax - lo16(z), 2.f * ay - hi16(z));
}

// ---------------- CSR propagation, single feature (H*R): 2 nodes/wave ----------------
// 32-lane subgroup per node; lane = uint = 2 bf16 channels (128B/edge); unroll 4
// (beg/end NOT wave-uniform here -> no readfirstlane)

__global__ __launch_bounds__(256) void k_prop1(const int* __restrict__ rowptr,
                                               const int2* __restrict__ emeta,
                                               const unsigned int* __restrict__ t,
                                               unsigned int* __restrict__ out, int N) {
    int wv = (blockIdx.x * 256 + threadIdx.x) >> 6;
    int lane = threadIdx.x & 63;
    int node = wv * 2 + (lane >> 5);
    int sl = lane & 31;
    if (node >= N) return;
    int beg = rowptr[node], end = rowptr[node + 1];
    float ax = 0.f, ay = 0.f;
    int j = beg;
    for (; j + 3 < end; j += 4) {
        int2 m0 = emeta[j], m1 = emeta[j + 1], m2 = emeta[j + 2], m3 = emeta[j + 3];
        unsigned int p0 = t[(size_t)m0.x * 32 + sl];
        unsigned int p1 = t[(size_t)m1.x * 32 + sl];
        unsigned int p2 = t[(size_t)m2.x * 32 + sl];
        unsigned int p3 = t[(size_t)m3.x * 32 + sl];
        float l0 = __int_as_float(m0.y), l1 = __int_as_float(m1.y);
        float l2 = __int_as_float(m2.y), l3 = __int_as_float(m3.y);
        ax = fmaf(l0, lo16(p0), ax); ay = fmaf(l0, hi16(p0), ay);
        ax = fmaf(l1, lo16(p1), ax); ay = fmaf(l1, hi16(p1), ay);
        ax = fmaf(l2, lo16(p2), ax); ay = fmaf(l2, hi16(p2), ay);
        ax = fmaf(l3, lo16(p3), ax); ay = fmaf(l3, hi16(p3), ay);
    }
    for (; j < end; ++j) {
        int2 m = emeta[j];
        unsigned int p = t[(size_t)m.x * 32 + sl];
        float l = __int_as_float(m.y);
        ax = fmaf(l, lo16(p), ax); ay = fmaf(l, hi16(p), ay);
    }
    out[(size_t)node * 32 + sl] = pack2(ax, ay);
}

__global__ __launch_bounds__(256) void k_prop2(const int* __restrict__ rowptr,
                                               const int2* __restrict__ emeta,
                                               const unsigned int* __restrict__ t,
                                               const unsigned int* __restrict__ t0,
                                               unsigned int* __restrict__ out, int N) {
    int wv = (blockIdx.x * 256 + threadIdx.x) >> 6;
    int lane = threadIdx.x & 63;
    int node = wv * 2 + (lane >> 5);
    int sl = lane & 31;
    if (node >= N) return;
    int beg = rowptr[node], end = rowptr[node + 1];
    float ax = 0.f, ay = 0.f;
    int j = beg;
    for (; j + 3 < end; j += 4) {
        int2 m0 = emeta[j], m1 = emeta[j + 1], m2 = emeta[j + 2], m3 = emeta[j + 3];
        unsigned int p0 = t[(size_t)m0.x * 32 + sl];
        unsigned int p1 = t[(size_t)m1.x * 32 + sl];
        unsigned int p2 = t[(size_t)m2.x * 32 + sl];
        unsigned int p3 = t[(size_t)m3.x * 32 + sl];
        float l0 = __int_as_float(m0.y), l1 = __int_as_float(m1.y);
        float l2 = __int_as_float(m2.y), l3 = __int_as_float(m3.y);
        ax = fmaf(l0, lo16(p0), ax); ay = fmaf(l0, hi16(p0), ay);
        ax = fmaf(l1, lo16(p1), ax); ay = fmaf(l1, hi16(p1), ay);
        ax = fmaf(l2, lo16(p2), ax); ay = fmaf(l2, hi16(p2), ay);
        ax = fmaf(l3, lo16(p3), ax); ay = fmaf(l3, hi16(p3), ay);
    }
    for (; j < end; ++j) {
        int2 m = emeta[j];
        unsigned int p = t[(size_t)m.x * 32 + sl];
        float l = __int_as_float(m.y);
        ax = fmaf(l, lo16(p), ax); ay = fmaf(l, hi16(p), ay);
    }
    size_t oi = (size_t)node * 32 + sl;
    unsigned int z = t0[oi];
    out[oi] = pack2(2.f * ax - lo16(z), 2.f * ay - hi16(z));
}

// ---------------- MFMA GEMM helpers ----------------
// wave computes 32 rows x 64 cols; k-slot: k = kt*32 + (lane>>4)*8 + e

static __device__ __forceinline__ bf16x8 ldA(const ushort* __restrict__ t, int stride,
                                             int row0, int lane, int kt, int N) {
    int row = row0 + (lane & 15);
    bf16x8 v = {};
    if (row < N) v = *(const bf16x8*)(t + (size_t)row * stride + kt * 32 + ((lane >> 4) << 3));
    return v;
}
static __device__ __forceinline__ bf16x8 ldB(const ushort* __restrict__ bp,
                                             int mt, int ct, int lane) {
    return *(const bf16x8*)(bp + ((((mt * 4) + ct) * 64 + lane) << 3));
}

#define MFMA(a, b, c) __builtin_amdgcn_mfma_f32_16x16x32_bf16(a, b, c, 0, 0, 0)

// ---------------- Pass A: Z(bf16), HR(bf16), preH(bf16) ----------------

__global__ __launch_bounds__(256) void k_gA(
    const ushort* __restrict__ XHb, const ushort* __restrict__ T1xh, const ushort* __restrict__ T2xh,
    const ushort* __restrict__ Bp,
    const float* __restrict__ bxz, const float* __restrict__ bhz,
    const float* __restrict__ bxr, const float* __restrict__ bhr,
    const float* __restrict__ bxh,
    const float* __restrict__ H,
    ushort* __restrict__ Zb, ushort* __restrict__ HRb, ushort* __restrict__ preHb, int N)
{
    int wid = blockIdx.x * 4 + (threadIdx.x >> 6);
    int lane = threadIdx.x & 63;
    int row0 = wid * 32;
    if (row0 >= N) return;

    f32x4 accZ[2][4], accR[2][4], accH[2][4];
    #pragma unroll
    for (int ct = 0; ct < 4; ++ct) {
        int col = ct * 16 + (lane & 15);
        float bz = bxz[col] + bhz[col];
        float br = bxr[col] + bhr[col];
        float bh = bxh[col];
        #pragma unroll
        for (int rt = 0; rt < 2; ++rt) {
            accZ[rt][ct] = (f32x4){bz, bz, bz, bz};
            accR[rt][ct] = (f32x4){br, br, br, br};
            accH[rt][ct] = (f32x4){bh, bh, bh, bh};
        }
    }

    const ushort* ins[6] = { XHb, T1xh, T2xh, XHb + 64, T1xh + 64, T2xh + 64 };

    #pragma unroll
    for (int m = 0; m < 6; ++m) {
        #pragma unroll
        for (int kt = 0; kt < 2; ++kt) {
            bf16x8 a0 = ldA(ins[m], 128, row0,      lane, kt, N);
            bf16x8 a1 = ldA(ins[m], 128, row0 + 16, lane, kt, N);
            int mt = m * 2 + kt;
            #pragma unroll
            for (int ct = 0; ct < 4; ++ct) {
                bf16x8 bz8 = ldB(Bp, mt, ct, lane);
                accZ[0][ct] = MFMA(a0, bz8, accZ[0][ct]);
                accZ[1][ct] = MFMA(a1, bz8, accZ[1][ct]);
                bf16x8 br8 = ldB(Bp, 12 + mt, ct, lane);
                accR[0][ct] = MFMA(a0, br8, accR[0][ct]);
                accR[1][ct] = MFMA(a1, br8, accR[1][ct]);
                if (m < 3) {
                    bf16x8 bh8 = ldB(Bp, 24 + mt, ct, lane);
                    accH[0][ct] = MFMA(a0, bh8, accH[0][ct]);
                    accH[1][ct] = MFMA(a1, bh8, accH[1][ct]);
                }
            }
        }
    }

    #pragma unroll
    for (int rt = 0; rt < 2; ++rt) {
        #pragma unroll
        for (int ct = 0; ct < 4; ++ct) {
            int col = ct * 16 + (lane & 15);
            #pragma unroll
            for (int r = 0; r < 4; ++r) {
                int row = row0 + rt * 16 + ((lane >> 4) << 2) + r;
                if (row < N) {
                    int o = row * CH + col;
                    float z = 1.f / (1.f + expf(-accZ[rt][ct][r]));
                    float rr = 1.f / (1.f + expf(-accR[rt][ct][r]));
                    float h = H[o];
                    Zb[o] = f2bf(z);
                    HRb[o] = f2bf(h * rr);
                    preHb[o] = f2bf(accH[rt][ct][r]);
                }
            }
        }
    }
}

// ---------------- Pass B: H_new = Z*H + (1-Z)*tanh(preH + hh-conv) ----------------

__global__ __launch_bounds__(256) void k_gB(
    const ushort* __restrict__ HRb, const ushort* __restrict__ T1, const ushort* __restrict__ T2,
    const ushort* __restrict__ Bp, const float* __restrict__ bhh,
    const ushort* __restrict__ Zb, const float* __restrict__ H,
    const ushort* __restrict__ preHb, float* __restrict__ out, int N)
{
    int wid = blockIdx.x * 4 + (threadIdx.x >> 6);
    int lane = threadIdx.x & 63;
    int row0 = wid * 32;
    if (row0 >= N) return;

    f32x4 acc[2][4];
    #pragma unroll
    for (int ct = 0; ct < 4; ++ct) {
        int col = ct * 16 + (lane & 15);
        float bh = bhh[col];
        #pragma unroll
        for (int rt = 0; rt < 2; ++rt) acc[rt][ct] = (f32x4){bh, bh, bh, bh};
    }

    const ushort* ins[3] = { HRb, T1, T2 };

    #pragma unroll
    for (int m = 0; m < 3; ++m) {
        #pragma unroll
        for (int kt = 0; kt < 2; ++kt) {
            bf16x8 a0 = ldA(ins[m], 64, row0,      lane, kt, N);
            bf16x8 a1 = ldA(ins[m], 64, row0 + 16, lane, kt, N);
            int mt = 30 + m * 2 + kt;
            #pragma unroll
            for (int ct = 0; ct < 4; ++ct) {
                bf16x8 b8 = ldB(Bp, mt, ct, lane);
                acc[0][ct] = MFMA(a0, b8, acc[0][ct]);
                acc[1][ct] = MFMA(a1, b8, acc[1][ct]);
            }
        }
    }

    #pragma unroll
    for (int rt = 0; rt < 2; ++rt) {
        #pragma unroll
        for (int ct = 0; ct < 4; ++ct) {
            int col = ct * 16 + (lane & 15);
            #pragma unroll
            for (int r = 0; r < 4; ++r) {
                int row = row0 + rt * 16 + ((lane >> 4) << 2) + r;
                if (row < N) {
                    int o = row * CH + col;
                    float pre = acc[rt][ct][r] + bf2f(preHb[o]);
                    float z = bf2f(Zb[o]);
                    float h = H[o];
                    out[o] = z * h + (1.f - z) * tanhf(pre);
                }
            }
        }
    }
}

// ---------------- launch ----------------

extern "C" void kernel_launch(void* const* d_in, const int* in_sizes, int n_in,
                              void* d_out, int out_size, void* d_ws, size_t ws_size,
                              hipStream_t stream) {
    const float* X   = (const float*)d_in[0];
    const int*   ei  = (const int*)d_in[1];
    const float* ew  = (const float*)d_in[2];
    const float* H   = (const float*)d_in[3];
    const float* Wxz = (const float*)d_in[4];
    const float* bxz = (const float*)d_in[5];
    const float* Whz = (const float*)d_in[6];
    const float* bhz = (const float*)d_in[7];
    const float* Wxr = (const float*)d_in[8];
    const float* bxr = (const float*)d_in[9];
    const float* Whr = (const float*)d_in[10];
    const float* bhr = (const float*)d_in[11];
    const float* Wxh = (const float*)d_in[12];
    const float* bxh = (const float*)d_in[13];
    const float* Whh = (const float*)d_in[14];
    const float* bhh = (const float*)d_in[15];

    const int N = in_sizes[0] / CH;
    const int E = in_sizes[2];
    const long long NC = (long long)N * CH;

    const int* srcI = ei;
    const int* dstI = ei + E;

    // ---- workspace layout ----
    char* p = (char*)d_ws;
    auto alloc = [&](size_t bytes) { char* r = p; p += (bytes + 255) & ~(size_t)255; return r; };
    int*    rowptr = (int*)alloc((size_t)(N + 1) * 4);
    int2*   emeta  = (int2*)alloc((size_t)E * 8);
    int*    erank  = (int*)alloc((size_t)E * 4);
    float*  deg    = (float*)alloc((size_t)N * 8);      // deg (N) + cnt (N), contiguous
    int*    cnt    = (int*)(deg + N);
    int*    bsum   = (int*)alloc(256 * 4);
    ushort* Bp     = (ushort*)alloc((size_t)36 * 4 * 64 * 8 * 2);
    ushort* XHb    = (ushort*)alloc((size_t)NC * 2 * 2);   // interleaved X|H [N][128]
    ushort* T1xh   = (ushort*)alloc((size_t)NC * 2 * 2);
    ushort* T2xh   = (ushort*)alloc((size_t)NC * 2 * 2);
    ushort* HRb    = (ushort*)alloc((size_t)NC * 2);       // planar [N][64]
    ushort* T1r    = (ushort*)alloc((size_t)NC * 2);
    ushort* T2r    = (ushort*)alloc((size_t)NC * 2);
    ushort* Zb     = (ushort*)alloc((size_t)NC * 2);
    ushort* preHb  = (ushort*)alloc((size_t)NC * 2);

    const int total4 = (int)(NC / 4);
    const int bE = (E + 255) / 256;
    const int bC = (total4 + 255) / 256;
    const int B  = (N + 2047) / 2048;                    // scan blocks (<=64)
    const int bW = (int)((N * 64 + 255) / 256);          // one wave per node
    const int bW2 = (int)((((N + 1) / 2) * 64 + 255) / 256); // 2 nodes per wave
    const int nW = (N + 31) / 32;
    const int bG = (nW + 3) / 4;

    // fused init: degree+hist+rank | cast | pack
    hipMemsetAsync(deg, 0, (size_t)N * 8, stream);
    k_init<<<bE + bC + 36, 256, 0, stream>>>(srcI, dstI, ew, deg, cnt, erank, E,
                                             (const float4*)X, (const float4*)H, XHb, total4,
                                             Wxz, Whz, Wxr, Whr, Wxh, Whh, Bp, bE, bC);

    // multi-block scan (+ fused rsqrt)
    k_scanA<<<B, 256, 0, stream>>>(cnt, rowptr, bsum, N);
    k_scanB<<<1, 64, 0, stream>>>(bsum, B);
    k_scanC<<<B, 256, 0, stream>>>(rowptr, bsum, deg, N, B);

    // atomic-free CSR scatter
    k_scatter<<<bE, 256, 0, stream>>>(srcI, dstI, ew, deg, rowptr, erank, emeta, E);

    // Chebyshev bases for X and H (fused, interleaved)
    k_prop_dual <<<bW, 256, 0, stream>>>(rowptr, emeta, (const unsigned int*)XHb,
                                         (unsigned int*)T1xh, N);
    k_prop_dual2<<<bW, 256, 0, stream>>>(rowptr, emeta, (const unsigned int*)T1xh,
                                         (const unsigned int*)XHb, (unsigned int*)T2xh, N);

    // Pass A: Z, H*R, preH
    k_gA<<<bG, 256, 0, stream>>>(XHb, T1xh, T2xh, Bp,
                                 bxz, bhz, bxr, bhr, bxh,
                                 H, Zb, HRb, preHb, N);

    // Chebyshev bases for H*R (2 nodes/wave)
    k_prop1<<<bW2, 256, 0, stream>>>(rowptr, emeta, (const unsigned int*)HRb,
                                     (unsigned int*)T1r, N);
    k_prop2<<<bW2, 256, 0, stream>>>(rowptr, emeta, (const unsigned int*)T1r,
                                     (const unsigned int*)HRb, (unsigned int*)T2r, N);

    // Pass B: H_new
    k_gB<<<bG, 256, 0, stream>>>(HRb, T1r, T2r, Bp, bhh, Zb, H, preHb, (float*)d_out, N);
}

// Round 11
// 283.978 us; speedup vs baseline: 1.1453x; 1.0151x over previous
//
#include <hip/hip_runtime.h>
#include <math.h>

#define CH 64   // channels (C_IN == C_OUT == 64)

typedef __attribute__((ext_vector_type(8))) short bf16x8;
typedef __attribute__((ext_vector_type(4))) float f32x4;

static __device__ __forceinline__ float bf2f(ushort u) {
    union { unsigned int i; float f; } v; v.i = ((unsigned int)u) << 16; return v.f;
}
static __device__ __forceinline__ ushort f2bf(float f) {
    union { float f; unsigned int i; } v; v.f = f;
    unsigned int lsb = (v.i >> 16) & 1;
    v.i += 0x7fffu + lsb;               // round-to-nearest-even
    return (ushort)(v.i >> 16);
}
static __device__ __forceinline__ unsigned int pack2(float a, float b) {
    return (unsigned int)f2bf(a) | ((unsigned int)f2bf(b) << 16);
}
static __device__ __forceinline__ float lo16(unsigned int u) { return bf2f((ushort)(u & 0xffffu)); }
static __device__ __forceinline__ float hi16(unsigned int u) { return bf2f((ushort)(u >> 16)); }

// ---------------- fused init: degree+hist+rank | bf16 cast | weight pack ----------------
// Chebyshev fold: with P2 = L*T1 stored (instead of T2 = 2*P2 - T0), the GEMM uses
//   W0' = W0 - W2,  W1' = W1,  W2' = 2*W2
// so both prop hops are the plain "gather-accumulate" kernel (no t0 read / combine).

__global__ __launch_bounds__(256) void k_init(
    const int* __restrict__ src, const int* __restrict__ dst,
    const float* __restrict__ w,
    float* __restrict__ deg, int* __restrict__ cnt, int* __restrict__ erank, int E,
    const float4* __restrict__ X, const float4* __restrict__ H,
    ushort* __restrict__ XHb, int total4,
    const float* __restrict__ Wxz, const float* __restrict__ Whz,
    const float* __restrict__ Wxr, const float* __restrict__ Whr,
    const float* __restrict__ Wxh, const float* __restrict__ Whh,
    ushort* __restrict__ Bp, int bE, int bC)
{
    int b = blockIdx.x;
    int tid = threadIdx.x;
    if (b < bE) {
        // degree over src, histogram+rank over dst
        int i = b * 256 + tid;
        if (i < E) {
            atomicAdd(&deg[src[i]], w[i]);
            erank[i] = atomicAdd(&cnt[dst[i]], 1);
        }
    } else if (b < bE + bC) {
        // cast X,H -> bf16, interleaved rows [X(64)|H(64)]
        int i = (b - bE) * 256 + tid;
        if (i < total4) {
            float4 x = X[i], h = H[i];
            int node = i >> 4, c4 = i & 15;
            ushort4 xb, hb;
            xb.x = f2bf(x.x); xb.y = f2bf(x.y); xb.z = f2bf(x.z); xb.w = f2bf(x.w);
            hb.x = f2bf(h.x); hb.y = f2bf(h.y); hb.z = f2bf(h.z); hb.w = f2bf(h.w);
            *(ushort4*)(XHb + (size_t)node * 128 + c4 * 4)      = xb;
            *(ushort4*)(XHb + (size_t)node * 128 + 64 + c4 * 4) = hb;
        }
    } else {
        // pack weights (Chebyshev-folded): Bp[mtg][ct][lane][e]
        // mtg: z=0..11, r=12..23, h(x)=24..29, hh=30..35
        // k-slot: k = kt*32 + (lane>>4)*8 + e (consistent A/B convention)
        int mtg = b - bE - bC;
        int ct = tid >> 6;
        int lane = tid & 63;
        const float* Wb; int m, kt;
        if (mtg < 12)      { int l = mtg;      m = l >> 1; kt = l & 1; Wb = (m < 3) ? Wxz : Whz; if (m >= 3) m -= 3; }
        else if (mtg < 24) { int l = mtg - 12; m = l >> 1; kt = l & 1; Wb = (m < 3) ? Wxr : Whr; if (m >= 3) m -= 3; }
        else if (mtg < 30) { int l = mtg - 24; m = l >> 1; kt = l & 1; Wb = Wxh; }
        else               { int l = mtg - 30; m = l >> 1; kt = l & 1; Wb = Whh; }
        int cout = ct * 16 + (lane & 15);
        ushort* dstp = Bp + ((((mtg * 4) + ct) * 64 + lane) << 3);
        #pragma unroll
        for (int e = 0; e < 8; ++e) {
            int cin = kt * 32 + ((lane >> 4) << 3) + e;
            float v = Wb[m * 4096 + cin * 64 + cout];
            if (m == 0)      v -= Wb[2 * 4096 + cin * 64 + cout];
            else if (m == 2) v *= 2.f;
            dstp[e] = f2bf(v);
        }
    }
}

// ---------------- 3-phase multi-block scan ----------------

__global__ __launch_bounds__(256) void k_scanA(const int* __restrict__ cnt,
                                               int* __restrict__ rowptr,
                                               int* __restrict__ bsum, int N) {
    __shared__ int ts[256];
    int tid = threadIdx.x;
    int base = blockIdx.x * 2048 + tid * 8;
    int v[8]; int s = 0;
    #pragma unroll
    for (int k = 0; k < 8; ++k) { int i = base + k; v[k] = (i < N) ? cnt[i] : 0; s += v[k]; }
    ts[tid] = s;
    __syncthreads();
    for (int off = 1; off < 256; off <<= 1) {
        int t = (tid >= off) ? ts[tid - off] : 0;
        __syncthreads();
        ts[tid] += t;
        __syncthreads();
    }
    int run = ts[tid] - s;
    #pragma unroll
    for (int k = 0; k < 8; ++k) { int i = base + k; if (i < N) rowptr[i] = run; run += v[k]; }
    if (tid == 255) bsum[blockIdx.x] = ts[255];
}

// wave-parallel scan of block sums (B <= 64)
__global__ void k_scanB(int* __restrict__ bsum, int B) {
    int lane = threadIdx.x;
    int v = (lane < B) ? bsum[lane] : 0;
    int incl = v;
    #pragma unroll
    for (int off = 1; off < 64; off <<= 1) {
        int t = __shfl_up(incl, off, 64);
        if (lane >= off) incl += t;
    }
    if (lane < B) bsum[lane] = incl - v;
    if (lane == B - 1) bsum[B] = incl;
}

__global__ __launch_bounds__(256) void k_scanC(int* __restrict__ rowptr,
                                               const int* __restrict__ bsum,
                                               float* __restrict__ deg, int N, int B) {
    int base = blockIdx.x * 2048 + threadIdx.x * 8;
    int add = bsum[blockIdx.x];
    #pragma unroll
    for (int k = 0; k < 8; ++k) {
        int i = base + k;
        if (i < N) {
            rowptr[i] += add;
            float d = deg[i];
            deg[i] = (d > 0.f) ? rsqrtf(fmaxf(d, 1e-12f)) : 0.f;
        }
    }
    if (blockIdx.x == 0 && threadIdx.x == 0) rowptr[N] = bsum[B];
}

// ---------------- atomic-free scatter: pos = rowptr[dst] + rank ----------------

__global__ __launch_bounds__(256) void k_scatter(const int* __restrict__ src,
                                                 const int* __restrict__ dst,
                                                 const float* __restrict__ w,
                                                 const float* __restrict__ dis,
                                                 const int* __restrict__ rowptr,
                                                 const int* __restrict__ erank,
                                                 int2* __restrict__ emeta, int E) {
    int e = blockIdx.x * 256 + threadIdx.x;
    if (e < E) {
        int d = dst[e], s = src[e];
        int pos = rowptr[d] + erank[e];
        float lw = -dis[s] * w[e] * dis[d];
        emeta[pos] = make_int2(s, __float_as_int(lw));
    }
}

// ---------------- CSR propagation, dual (interleaved X|H rows, 256B/edge) ----------------
// one wave per node; lane = uint = 2 bf16 channels; unroll 4.
// beg/end wave-uniform (1 wave = 1 node): readfirstlane -> scalar emeta loads.
// Used for BOTH hops (Chebyshev combine folded into packed weights).

__global__ __launch_bounds__(256) void k_prop_dual(const int* __restrict__ rowptr,
                                                   const int2* __restrict__ emeta,
                                                   const unsigned int* __restrict__ t,
                                                   unsigned int* __restrict__ o, int N) {
    int wid = (blockIdx.x * 256 + threadIdx.x) >> 6;
    int lane = threadIdx.x & 63;
    if (wid >= N) return;
    int beg = __builtin_amdgcn_readfirstlane(rowptr[wid]);
    int end = __builtin_amdgcn_readfirstlane(rowptr[wid + 1]);
    float ax = 0.f, ay = 0.f;
    int j = beg;
    for (; j + 3 < end; j += 4) {
        int2 m0 = emeta[j], m1 = emeta[j + 1], m2 = emeta[j + 2], m3 = emeta[j + 3];
        unsigned int p0 = t[(size_t)m0.x * 64 + lane];
        unsigned int p1 = t[(size_t)m1.x * 64 + lane];
        unsigned int p2 = t[(size_t)m2.x * 64 + lane];
        unsigned int p3 = t[(size_t)m3.x * 64 + lane];
        float l0 = __int_as_float(m0.y), l1 = __int_as_float(m1.y);
        float l2 = __int_as_float(m2.y), l3 = __int_as_float(m3.y);
        ax = fmaf(l0, lo16(p0), ax); ay = fmaf(l0, hi16(p0), ay);
        ax = fmaf(l1, lo16(p1), ax); ay = fmaf(l1, hi16(p1), ay);
        ax = fmaf(l2, lo16(p2), ax); ay = fmaf(l2, hi16(p2), ay);
        ax = fmaf(l3, lo16(p3), ax); ay = fmaf(l3, hi16(p3), ay);
    }
    for (; j < end; ++j) {
        int2 m = emeta[j];
        unsigned int p = t[(size_t)m.x * 64 + lane];
        float l = __int_as_float(m.y);
        ax = fmaf(l, lo16(p), ax); ay = fmaf(l, hi16(p), ay);
    }
    o[(size_t)wid * 64 + lane] = pack2(ax, ay);
}

// ---------------- CSR propagation, single feature (H*R): 2 nodes/wave ----------------
// 32-lane subgroup per node; lane = uint = 2 bf16 channels (128B/edge); unroll 4.
// Used for BOTH hops of the HR chain.

__global__ __launch_bounds__(256) void k_prop1(const int* __restrict__ rowptr,
                                               const int2* __restrict__ emeta,
                                               const unsigned int* __restrict__ t,
                                               unsigned int* __restrict__ out, int N) {
    int wv = (blockIdx.x * 256 + threadIdx.x) >> 6;
    int lane = threadIdx.x & 63;
    int node = wv * 2 + (lane >> 5);
    int sl = lane & 31;
    if (node >= N) return;
    int beg = rowptr[node], end = rowptr[node + 1];
    float ax = 0.f, ay = 0.f;
    int j = beg;
    for (; j + 3 < end; j += 4) {
        int2 m0 = emeta[j], m1 = emeta[j + 1], m2 = emeta[j + 2], m3 = emeta[j + 3];
        unsigned int p0 = t[(size_t)m0.x * 32 + sl];
        unsigned int p1 = t[(size_t)m1.x * 32 + sl];
        unsigned int p2 = t[(size_t)m2.x * 32 + sl];
        unsigned int p3 = t[(size_t)m3.x * 32 + sl];
        float l0 = __int_as_float(m0.y), l1 = __int_as_float(m1.y);
        float l2 = __int_as_float(m2.y), l3 = __int_as_float(m3.y);
        ax = fmaf(l0, lo16(p0), ax); ay = fmaf(l0, hi16(p0), ay);
        ax = fmaf(l1, lo16(p1), ax); ay = fmaf(l1, hi16(p1), ay);
        ax = fmaf(l2, lo16(p2), ax); ay = fmaf(l2, hi16(p2), ay);
        ax = fmaf(l3, lo16(p3), ax); ay = fmaf(l3, hi16(p3), ay);
    }
    for (; j < end; ++j) {
        int2 m = emeta[j];
        unsigned int p = t[(size_t)m.x * 32 + sl];
        float l = __int_as_float(m.y);
        ax = fmaf(l, lo16(p), ax); ay = fmaf(l, hi16(p), ay);
    }
    out[(size_t)node * 32 + sl] = pack2(ax, ay);
}

// ---------------- MFMA GEMM helpers ----------------
// wave computes 32 rows x 64 cols; k-slot: k = kt*32 + (lane>>4)*8 + e

static __device__ __forceinline__ bf16x8 ldA(const ushort* __restrict__ t, int stride,
                                             int row0, int lane, int kt, int N) {
    int row = row0 + (lane & 15);
    bf16x8 v = {};
    if (row < N) v = *(const bf16x8*)(t + (size_t)row * stride + kt * 32 + ((lane >> 4) << 3));
    return v;
}
static __device__ __forceinline__ bf16x8 ldB(const ushort* __restrict__ bp,
                                             int mt, int ct, int lane) {
    return *(const bf16x8*)(bp + ((((mt * 4) + ct) * 64 + lane) << 3));
}

#define MFMA(a, b, c) __builtin_amdgcn_mfma_f32_16x16x32_bf16(a, b, c, 0, 0, 0)

// ---------------- Pass A: Z(bf16), HR(bf16), preH(bf16) ----------------

__global__ __launch_bounds__(256) void k_gA(
    const ushort* __restrict__ XHb, const ushort* __restrict__ T1xh, const ushort* __restrict__ T2xh,
    const ushort* __restrict__ Bp,
    const float* __restrict__ bxz, const float* __restrict__ bhz,
    const float* __restrict__ bxr, const float* __restrict__ bhr,
    const float* __restrict__ bxh,
    const float* __restrict__ H,
    ushort* __restrict__ Zb, ushort* __restrict__ HRb, ushort* __restrict__ preHb, int N)
{
    int wid = blockIdx.x * 4 + (threadIdx.x >> 6);
    int lane = threadIdx.x & 63;
    int row0 = wid * 32;
    if (row0 >= N) return;

    f32x4 accZ[2][4], accR[2][4], accH[2][4];
    #pragma unroll
    for (int ct = 0; ct < 4; ++ct) {
        int col = ct * 16 + (lane & 15);
        float bz = bxz[col] + bhz[col];
        float br = bxr[col] + bhr[col];
        float bh = bxh[col];
        #pragma unroll
        for (int rt = 0; rt < 2; ++rt) {
            accZ[rt][ct] = (f32x4){bz, bz, bz, bz};
            accR[rt][ct] = (f32x4){br, br, br, br};
            accH[rt][ct] = (f32x4){bh, bh, bh, bh};
        }
    }

    const ushort* ins[6] = { XHb, T1xh, T2xh, XHb + 64, T1xh + 64, T2xh + 64 };

    #pragma unroll
    for (int m = 0; m < 6; ++m) {
        #pragma unroll
        for (int kt = 0; kt < 2; ++kt) {
            bf16x8 a0 = ldA(ins[m], 128, row0,      lane, kt, N);
            bf16x8 a1 = ldA(ins[m], 128, row0 + 16, lane, kt, N);
            int mt = m * 2 + kt;
            #pragma unroll
            for (int ct = 0; ct < 4; ++ct) {
                bf16x8 bz8 = ldB(Bp, mt, ct, lane);
                accZ[0][ct] = MFMA(a0, bz8, accZ[0][ct]);
                accZ[1][ct] = MFMA(a1, bz8, accZ[1][ct]);
                bf16x8 br8 = ldB(Bp, 12 + mt, ct, lane);
                accR[0][ct] = MFMA(a0, br8, accR[0][ct]);
                accR[1][ct] = MFMA(a1, br8, accR[1][ct]);
                if (m < 3) {
                    bf16x8 bh8 = ldB(Bp, 24 + mt, ct, lane);
                    accH[0][ct] = MFMA(a0, bh8, accH[0][ct]);
                    accH[1][ct] = MFMA(a1, bh8, accH[1][ct]);
                }
            }
        }
    }

    #pragma unroll
    for (int rt = 0; rt < 2; ++rt) {
        #pragma unroll
        for (int ct = 0; ct < 4; ++ct) {
            int col = ct * 16 + (lane & 15);
            #pragma unroll
            for (int r = 0; r < 4; ++r) {
                int row = row0 + rt * 16 + ((lane >> 4) << 2) + r;
                if (row < N) {
                    int o = row * CH + col;
                    float z = 1.f / (1.f + expf(-accZ[rt][ct][r]));
                    float rr = 1.f / (1.f + expf(-accR[rt][ct][r]));
                    float h = H[o];
                    Zb[o] = f2bf(z);
                    HRb[o] = f2bf(h * rr);
                    preHb[o] = f2bf(accH[rt][ct][r]);
                }
            }
        }
    }
}

// ---------------- Pass B: H_new = Z*H + (1-Z)*tanh(preH + hh-conv) ----------------

__global__ __launch_bounds__(256) void k_gB(
    const ushort* __restrict__ HRb, const ushort* __restrict__ T1, const ushort* __restrict__ T2,
    const ushort* __restrict__ Bp, const float* __restrict__ bhh,
    const ushort* __restrict__ Zb, const float* __restrict__ H,
    const ushort* __restrict__ preHb, float* __restrict__ out, int N)
{
    int wid = blockIdx.x * 4 + (threadIdx.x >> 6);
    int lane = threadIdx.x & 63;
    int row0 = wid * 32;
    if (row0 >= N) return;

    f32x4 acc[2][4];
    #pragma unroll
    for (int ct = 0; ct < 4; ++ct) {
        int col = ct * 16 + (lane & 15);
        float bh = bhh[col];
        #pragma unroll
        for (int rt = 0; rt < 2; ++rt) acc[rt][ct] = (f32x4){bh, bh, bh, bh};
    }

    const ushort* ins[3] = { HRb, T1, T2 };

    #pragma unroll
    for (int m = 0; m < 3; ++m) {
        #pragma unroll
        for (int kt = 0; kt < 2; ++kt) {
            bf16x8 a0 = ldA(ins[m], 64, row0,      lane, kt, N);
            bf16x8 a1 = ldA(ins[m], 64, row0 + 16, lane, kt, N);
            int mt = 30 + m * 2 + kt;
            #pragma unroll
            for (int ct = 0; ct < 4; ++ct) {
                bf16x8 b8 = ldB(Bp, mt, ct, lane);
                acc[0][ct] = MFMA(a0, b8, acc[0][ct]);
                acc[1][ct] = MFMA(a1, b8, acc[1][ct]);
            }
        }
    }

    #pragma unroll
    for (int rt = 0; rt < 2; ++rt) {
        #pragma unroll
        for (int ct = 0; ct < 4; ++ct) {
            int col = ct * 16 + (lane & 15);
            #pragma unroll
            for (int r = 0; r < 4; ++r) {
                int row = row0 + rt * 16 + ((lane >> 4) << 2) + r;
                if (row < N) {
                    int o = row * CH + col;
                    float pre = acc[rt][ct][r] + bf2f(preHb[o]);
                    float z = bf2f(Zb[o]);
                    float h = H[o];
                    out[o] = z * h + (1.f - z) * tanhf(pre);
                }
            }
        }
    }
}

// ---------------- launch ----------------

extern "C" void kernel_launch(void* const* d_in, const int* in_sizes, int n_in,
                              void* d_out, int out_size, void* d_ws, size_t ws_size,
                              hipStream_t stream) {
    const float* X   = (const float*)d_in[0];
    const int*   ei  = (const int*)d_in[1];
    const float* ew  = (const float*)d_in[2];
    const float* H   = (const float*)d_in[3];
    const float* Wxz = (const float*)d_in[4];
    const float* bxz = (const float*)d_in[5];
    const float* Whz = (const float*)d_in[6];
    const float* bhz = (const float*)d_in[7];
    const float* Wxr = (const float*)d_in[8];
    const float* bxr = (const float*)d_in[9];
    const float* Whr = (const float*)d_in[10];
    const float* bhr = (const float*)d_in[11];
    const float* Wxh = (const float*)d_in[12];
    const float* bxh = (const float*)d_in[13];
    const float* Whh = (const float*)d_in[14];
    const float* bhh = (const float*)d_in[15];

    const int N = in_sizes[0] / CH;
    const int E = in_sizes[2];
    const long long NC = (long long)N * CH;

    const int* srcI = ei;
    const int* dstI = ei + E;

    // ---- workspace layout ----
    char* p = (char*)d_ws;
    auto alloc = [&](size_t bytes) { char* r = p; p += (bytes + 255) & ~(size_t)255; return r; };
    int*    rowptr = (int*)alloc((size_t)(N + 1) * 4);
    int2*   emeta  = (int2*)alloc((size_t)E * 8);
    int*    erank  = (int*)alloc((size_t)E * 4);
    float*  deg    = (float*)alloc((size_t)N * 8);      // deg (N) + cnt (N), contiguous
    int*    cnt    = (int*)(deg + N);
    int*    bsum   = (int*)alloc(256 * 4);
    ushort* Bp     = (ushort*)alloc((size_t)36 * 4 * 64 * 8 * 2);
    ushort* XHb    = (ushort*)alloc((size_t)NC * 2 * 2);   // interleaved X|H [N][128]
    ushort* T1xh   = (ushort*)alloc((size_t)NC * 2 * 2);
    ushort* T2xh   = (ushort*)alloc((size_t)NC * 2 * 2);   // holds P2 = L*T1
    ushort* HRb    = (ushort*)alloc((size_t)NC * 2);       // planar [N][64]
    ushort* T1r    = (ushort*)alloc((size_t)NC * 2);
    ushort* T2r    = (ushort*)alloc((size_t)NC * 2);       // holds P2r = L*T1r
    ushort* Zb     = (ushort*)alloc((size_t)NC * 2);
    ushort* preHb  = (ushort*)alloc((size_t)NC * 2);

    const int total4 = (int)(NC / 4);
    const int bE = (E + 255) / 256;
    const int bC = (total4 + 255) / 256;
    const int B  = (N + 2047) / 2048;                    // scan blocks (<=64)
    const int bW = (int)((N * 64 + 255) / 256);          // one wave per node
    const int bW2 = (int)((((N + 1) / 2) * 64 + 255) / 256); // 2 nodes per wave
    const int nW = (N + 31) / 32;
    const int bG = (nW + 3) / 4;

    // fused init: degree+hist+rank | cast | pack (Chebyshev-folded weights)
    hipMemsetAsync(deg, 0, (size_t)N * 8, stream);
    k_init<<<bE + bC + 36, 256, 0, stream>>>(srcI, dstI, ew, deg, cnt, erank, E,
                                             (const float4*)X, (const float4*)H, XHb, total4,
                                             Wxz, Whz, Wxr, Whr, Wxh, Whh, Bp, bE, bC);

    // multi-block scan (+ fused rsqrt)
    k_scanA<<<B, 256, 0, stream>>>(cnt, rowptr, bsum, N);
    k_scanB<<<1, 64, 0, stream>>>(bsum, B);
    k_scanC<<<B, 256, 0, stream>>>(rowptr, bsum, deg, N, B);

    // atomic-free CSR scatter
    k_scatter<<<bE, 256, 0, stream>>>(srcI, dstI, ew, deg, rowptr, erank, emeta, E);

    // Chebyshev bases for X and H: T1 = L*XH, P2 = L*T1 (combine folded into weights)
    k_prop_dual<<<bW, 256, 0, stream>>>(rowptr, emeta, (const unsigned int*)XHb,
                                        (unsigned int*)T1xh, N);
    k_prop_dual<<<bW, 256, 0, stream>>>(rowptr, emeta, (const unsigned int*)T1xh,
                                        (unsigned int*)T2xh, N);

    // Pass A: Z, H*R, preH
    k_gA<<<bG, 256, 0, stream>>>(XHb, T1xh, T2xh, Bp,
                                 bxz, bhz, bxr, bhr, bxh,
                                 H, Zb, HRb, preHb, N);

    // Chebyshev bases for H*R: T1r = L*HR, P2r = L*T1r
    k_prop1<<<bW2, 256, 0, stream>>>(rowptr, emeta, (const unsigned int*)HRb,
                                     (unsigned int*)T1r, N);
    k_prop1<<<bW2, 256, 0, stream>>>(rowptr, emeta, (const unsigned int*)T1r,
                                     (unsigned int*)T2r, N);

    // Pass B: H_new
    k_gB<<<bG, 256, 0, stream>>>(HRb, T1r, T2r, Bp, bhh, Zb, H, preHb, (float*)d_out, N);
}